// Round 7
// baseline (121.697 us; speedup 1.0000x reference)
//
#include <hip/hip_runtime.h>
#include <hip/hip_bf16.h>
#include <stdint.h>

typedef __bf16 bf16_t;
typedef __bf16 bf16x4 __attribute__((ext_vector_type(4)));
typedef __bf16 bf16x8 __attribute__((ext_vector_type(8)));
typedef float  f32x4  __attribute__((ext_vector_type(4)));

#define WAITVM(N) asm volatile("s_waitcnt vmcnt(" #N ")" ::: "memory")

// ---- workspace layout (bytes) ----
static constexpr size_t WT_OFF = 0;                    // Wt bf16 [384][1024] = 768 KB
static constexpr size_t Q_OFF  = (size_t)1 << 20;      // q bf16 [16384][128] = 4 MB
static constexpr size_t K_OFF  = Q_OFF + ((size_t)4 << 20);
static constexpr size_t VT_OFF = K_OFF + ((size_t)4 << 20);  // vT bf16 [8][128][2048] = 4 MB

__device__ __forceinline__ void g2lds16(const void* g, void* l) {
  __builtin_amdgcn_global_load_lds(
      (__attribute__((address_space(1))) void*)(g),
      (__attribute__((address_space(3))) void*)(l), 16, 0, 0);
}

// ---------------- W transpose: W[1024][128] fp32 -> Wt[384][1024] bf16 ----------------
__global__ __launch_bounds__(256) void wt_kernel(const float* __restrict__ Wq,
                                                 const float* __restrict__ Wk,
                                                 const float* __restrict__ Wv,
                                                 bf16_t* __restrict__ wt) {
  __shared__ float tile[64][129];
  int wi = blockIdx.x >> 4;   // 0..2
  int ct = blockIdx.x & 15;   // 0..15 -> c0
  const float* W = (wi == 0) ? Wq : ((wi == 1) ? Wk : Wv);
  int c0 = ct * 64;
  int tid = threadIdx.x;
  for (int i = 0; i < 32; ++i) {
    int idx = i * 256 + tid;
    int c = idx >> 7, n = idx & 127;
    tile[c][n] = W[(size_t)(c0 + c) * 128 + n];   // coalesced read
  }
  __syncthreads();
  for (int i = 0; i < 32; ++i) {
    int idx = i * 256 + tid;
    int n = idx >> 6, c = idx & 63;
    wt[(size_t)(wi * 128 + n) * 1024 + c0 + c] = (bf16_t)tile[c][n];  // coalesced-ish write
  }
}

// ---------------- fused QKV projection v7: t64 x n128 tile, 4 waves (2t x 2n) -------
// Grid 768 = 3 slices x 256 t-tiles(64), XCD-chunked. Block 256 thr = 4 waves.
// Wave tile t32 x n64: per BK=64 step: 8 wf loads + 4 stage + WAITVM(12) + barrier +
// 8 ds_read + 16 MFMA + barrier. 3 blocks/CU -> 12 waves/CU = 3/SIMD.
__global__ __launch_bounds__(256) void proj_kernel(const float* __restrict__ x,
                                                   const bf16_t* __restrict__ wt,
                                                   bf16_t* __restrict__ q,
                                                   bf16_t* __restrict__ k,
                                                   bf16_t* __restrict__ vT) {
  __shared__ __align__(16) char Blds[2][16384];  // x tile [64 t][64 k] f32, 16B-chunk XOR swz

  int wgid = (blockIdx.x & 7) * 96 + (blockIdx.x >> 3);
  int t_tile = wgid / 3;
  int slice = wgid % 3;          // 0=Q, 1=K, 2=V
  int n0 = slice * 128;
  int t0 = t_tile * 64;

  int tid = threadIdx.x;
  int lane = tid & 63;
  int wv = tid >> 6;             // wave: (wv&1)=n-half, (wv>>1)=t-half
  int nh = wv & 1, th = wv >> 1;
  int lq = lane & 15, grp = lane >> 4;

  const char* xb = (const char*)x;   // global row stride 4096 B

  f32x4 acc[4][2];
#pragma unroll
  for (int a = 0; a < 4; ++a)
#pragma unroll
    for (int s = 0; s < 2; ++s) acc[a][s] = (f32x4){0.f, 0.f, 0.f, 0.f};

  const bf16_t* wbase = wt + (size_t)(n0 + nh * 64 + lq) * 1024 + grp * 8;

  // stage x tile [64][64] f32 into Blds[bi]; LDS linear, source pre-swizzled (rule 21)
  auto stageB = [&](int bi, int k0) {
#pragma unroll
    for (int i = 0; i < 4; ++i) {
      int off = i * 4096 + tid * 16;
      int row = off >> 8;              // 0..63
      int c = (off >> 4) & 15;         // 16B chunk in row
      const char* src = xb + (size_t)(t0 + row) * 4096 + (size_t)k0 * 4
                        + ((c ^ (row & 15)) << 4);
      g2lds16(src, &Blds[bi][off]);
    }
  };

  stageB(0, 0);

  for (int ks = 0; ks < 16; ++ks) {
    int cur = ks & 1;
    int k0 = ks * 64;

    // wt register loads for THIS step (global, no LDS dep)
    bf16x8 wf[4][2];
#pragma unroll
    for (int kh = 0; kh < 2; ++kh)
#pragma unroll
      for (int a = 0; a < 4; ++a)
        wf[a][kh] = *(const bf16x8*)(wbase + (size_t)(a * 16) * 1024 + k0 + kh * 32);

    if (ks < 15) {
      stageB(cur ^ 1, (ks + 1) * 64);
      WAITVM(12);              // drains stage(ks); wf(ks)+stage(ks+1) may stay in flight
    } else {
      WAITVM(8);               // only wf(15) may stay in flight
    }
    __builtin_amdgcn_s_barrier();
    __builtin_amdgcn_sched_barrier(0);

    bf16x8 xf[2][2];
#pragma unroll
    for (int sub = 0; sub < 2; ++sub) {
      int row = th * 32 + sub * 16 + lq;
#pragma unroll
      for (int kh = 0; kh < 2; ++kh) {
        int c0 = kh * 8 + grp * 2;
        float4 f0 = *(const float4*)(&Blds[cur][row * 256 + (((c0)     ^ (row & 15)) << 4)]);
        float4 f1 = *(const float4*)(&Blds[cur][row * 256 + (((c0 + 1) ^ (row & 15)) << 4)]);
        bf16x8 v;
        v[0] = (bf16_t)f0.x; v[1] = (bf16_t)f0.y; v[2] = (bf16_t)f0.z; v[3] = (bf16_t)f0.w;
        v[4] = (bf16_t)f1.x; v[5] = (bf16_t)f1.y; v[6] = (bf16_t)f1.z; v[7] = (bf16_t)f1.w;
        xf[sub][kh] = v;
      }
    }

#pragma unroll
    for (int kh = 0; kh < 2; ++kh)
#pragma unroll
      for (int a = 0; a < 4; ++a)
#pragma unroll
        for (int sub = 0; sub < 2; ++sub)
          acc[a][sub] = __builtin_amdgcn_mfma_f32_16x16x32_bf16(wf[a][kh], xf[sub][kh],
                                                                acc[a][sub], 0, 0, 0);
    __builtin_amdgcn_s_barrier();   // all waves done with buf cur (no vm drain)
  }

  if (slice < 2) {   // Q or K row-major: [t][128]
    bf16_t* dst = (slice == 0) ? q : k;
#pragma unroll
    for (int a = 0; a < 4; ++a)
#pragma unroll
      for (int sub = 0; sub < 2; ++sub) {
        bf16x4 o;
        o[0] = (bf16_t)acc[a][sub][0]; o[1] = (bf16_t)acc[a][sub][1];
        o[2] = (bf16_t)acc[a][sub][2]; o[3] = (bf16_t)acc[a][sub][3];
        *(bf16x4*)(dst + (size_t)(t0 + th * 32 + sub * 16 + lq) * 128
                   + nh * 64 + a * 16 + grp * 4) = o;
      }
  } else {           // V transposed: vT[b][d][t]
    int b = t0 >> 11;
#pragma unroll
    for (int a = 0; a < 4; ++a)
#pragma unroll
      for (int sub = 0; sub < 2; ++sub) {
        int tt = (t0 + th * 32 + sub * 16 + lq) & 2047;
#pragma unroll
        for (int r = 0; r < 4; ++r) {
          int d = nh * 64 + a * 16 + grp * 4 + r;
          vT[(size_t)b * 128 * 2048 + (size_t)d * 2048 + tt] = (bf16_t)acc[a][sub][r];
        }
      }
  }
}

// ---------------- flash attention v7: intra-block kv-split, per-wave pipeline -------
// 1024 blocks = 8 b (XCD-pinned) x 128 q-tiles(16 rows), heavy-first; 2 waves/block.
// Wave w handles kv-tiles {w, w+2, ...} of 32 kv each: private dbuf K in LDS (g2lds),
// V prefetched to regs one tile ahead; counted per-wave vmcnt; NO barriers in loop.
// Final: online-softmax merge of the two partials via LDS + one __syncthreads.
__global__ __launch_bounds__(128) void attn_kernel(const bf16_t* __restrict__ q,
                                                   const bf16_t* __restrict__ k,
                                                   const bf16_t* __restrict__ vT,
                                                   float* __restrict__ out) {
  __shared__ __align__(16) char lds[34816];  // [w*16K: K dbuf 2x8K] x2 | 32K+w*1K: P

  int tid = threadIdx.x;
  int lane = tid & 63;
  int w = tid >> 6;                  // kv-split index
  int lq = lane & 15, grp = lane >> 4;
  int b = blockIdx.x & 7;            // XCD-pinned batch
  int qt = 127 - (blockIdx.x >> 3);  // heavy (long prefix) first; 16 q-rows
  int tq = qt * 16 + lq;

  bf16x8 qf[4];
  const bf16_t* qrow = q + ((size_t)b * 2048 + tq) * 128 + grp * 8;
#pragma unroll
  for (int ks = 0; ks < 4; ++ks) qf[ks] = *(const bf16x8*)(qrow + ks * 32);  // 4 vm (oldest)

  float mrun = -__builtin_inff();
  float lsum = 0.f;
  f32x4 accO[8];
#pragma unroll
  for (int i = 0; i < 8; ++i) accO[i] = (f32x4){0.f, 0.f, 0.f, 0.f};

  const float scale = 1.0f / 32.0f;
  const char* kbase = (const char*)(k + (size_t)b * 2048 * 128);
  const bf16_t* vb = vT + (size_t)b * 128 * 2048;

  auto stageK = [&](int bi, int kv0) {   // 8K tile [32 kv][256B], per-wave private
#pragma unroll
    for (int i = 0; i < 8; ++i) {
      int off = i * 1024 + lane * 16;
      int row = off >> 8;              // 0..31
      int c = (off >> 4) & 15;
      const char* src = kbase + (size_t)(kv0 + row) * 256 + ((c ^ (row & 7)) << 4);
      g2lds16(src, &lds[w * 16384 + bi * 8192 + off]);
    }
  };

  bf16x8 vf[8];
  auto loadV = [&](int kv0) {            // V^T frags direct to regs (8 vm)
#pragma unroll
    for (int mf = 0; mf < 8; ++mf)
      vf[mf] = *(const bf16x8*)(vb + (size_t)(mf * 16 + lq) * 2048 + kv0 + grp * 8);
  };

  int nt = (qt >> 1) + 1;                // kv tiles of 32 covering [0, qt*16+16)
  int cnt = (nt - w + 1) >> 1;           // this wave's tile count (tiles w, w+2, ...)

  if (cnt > 0) { stageK(0, w * 32); loadV(w * 32); }

  for (int i = 0; i < cnt; ++i) {
    int kv0 = (w + 2 * i) * 32;
    int cur = i & 1;
    bool pre = (i + 1 < cnt);
    if (pre) { stageK(cur ^ 1, kv0 + 64); WAITVM(16); }   // K(t) ready; K(t+1)+V(t) fly
    else     { WAITVM(8); }                               // K(t) ready; V(t) flies
    __builtin_amdgcn_sched_barrier(0);

    // S^T = K · Q^T : [32 kv][16 q]
    f32x4 s[2];
    s[0] = (f32x4){0.f, 0.f, 0.f, 0.f};
    s[1] = (f32x4){0.f, 0.f, 0.f, 0.f};
#pragma unroll
    for (int ks = 0; ks < 4; ++ks) {
#pragma unroll
      for (int mf = 0; mf < 2; ++mf) {
        int row = mf * 16 + lq;
        bf16x8 kf = *(const bf16x8*)(&lds[w * 16384 + cur * 8192 + row * 256
                                          + (((ks * 4 + grp) ^ (row & 7)) << 4)]);
        s[mf] = __builtin_amdgcn_mfma_f32_16x16x32_bf16(kf, qf[ks], s[mf], 0, 0, 0);
      }
    }

    // online softmax; lane owns q-row tq, holds 8 kv values
    float z[2][4];
    float pmax = -__builtin_inff();
#pragma unroll
    for (int f = 0; f < 2; ++f) {
#pragma unroll
      for (int r = 0; r < 4; ++r) {
        int kv = kv0 + f * 16 + grp * 4 + r;
        float zz = s[f][r] * scale;
        zz = (kv <= tq) ? zz : -__builtin_inff();
        z[f][r] = zz;
        pmax = fmaxf(pmax, zz);
      }
    }
    pmax = fmaxf(pmax, __shfl_xor(pmax, 16, 64));
    pmax = fmaxf(pmax, __shfl_xor(pmax, 32, 64));
    float mnew = fmaxf(mrun, pmax);
    float msub = fmaxf(mnew, -3e38f);    // NaN guard: fully-masked tile -> mnew=-inf
    float corr = __expf(mrun - msub);
    float p[2][4];
    float psum = 0.f;
#pragma unroll
    for (int f = 0; f < 2; ++f) {
#pragma unroll
      for (int r = 0; r < 4; ++r) {
        p[f][r] = __expf(z[f][r] - msub);
        psum += p[f][r];
      }
    }
    psum += __shfl_xor(psum, 16, 64);
    psum += __shfl_xor(psum, 32, 64);
    lsum = lsum * corr + psum;
    mrun = mnew;
#pragma unroll
    for (int i2 = 0; i2 < 8; ++i2) accO[i2] *= corr;

    // pack P^T (wave-private 1KB region; intra-wave lgkm ordering)
#pragma unroll
    for (int f = 0; f < 2; ++f) {
      bf16x4 pw;
      pw[0] = (bf16_t)p[f][0]; pw[1] = (bf16_t)p[f][1];
      pw[2] = (bf16_t)p[f][2]; pw[3] = (bf16_t)p[f][3];
      *(bf16x4*)(&lds[32768 + w * 1024 + ((f * 2 + (grp >> 1)) << 8)
                      + lq * 16 + ((grp & 1) << 3)]) = pw;
    }

    if (pre) { WAITVM(8); }   // V(t) regs ready; K(t+1) stays in flight
    else     { WAITVM(0); }
    __builtin_amdgcn_sched_barrier(0);

    // O^T += V^T · P^T (V in regs, single k-step of 32)
    bf16x8 pf = *(const bf16x8*)(&lds[32768 + w * 1024 + (grp << 8) + lq * 16]);
#pragma unroll
    for (int mf = 0; mf < 8; ++mf)
      accO[mf] = __builtin_amdgcn_mfma_f32_16x16x32_bf16(vf[mf], pf, accO[mf], 0, 0, 0);

    if (pre) loadV(kv0 + 64);   // issue next V after PV consumed vf (WAR-safe in-order)
  }

  // ---- merge the two kv-split partials via LDS (single barrier) ----
#pragma unroll
  for (int mf = 0; mf < 8; ++mf)
    *(f32x4*)(&lds[w * 16384 + lane * 128 + mf * 16]) = accO[mf];
  *(float*)(&lds[w * 16384 + 8192 + lane * 8])     = mrun;
  *(float*)(&lds[w * 16384 + 8192 + lane * 8 + 4]) = lsum;
  __syncthreads();

  float m0 = *(const float*)(&lds[8192 + lane * 8]);
  float l0 = *(const float*)(&lds[8192 + lane * 8 + 4]);
  float m1 = *(const float*)(&lds[16384 + 8192 + lane * 8]);
  float l1 = *(const float*)(&lds[16384 + 8192 + lane * 8 + 4]);
  float m = fmaxf(m0, m1);
  float c0 = __expf(m0 - m), c1 = __expf(m1 - m);
  float inv = 1.0f / (l0 * c0 + l1 * c1);
  float* orow = out + ((size_t)b * 2048 + tq) * 128;
#pragma unroll
  for (int j = 0; j < 4; ++j) {
    int mf = w * 4 + j;
    f32x4 O0 = *(const f32x4*)(&lds[lane * 128 + mf * 16]);
    f32x4 O1 = *(const f32x4*)(&lds[16384 + lane * 128 + mf * 16]);
    f32x4 o;
#pragma unroll
    for (int e = 0; e < 4; ++e) o[e] = (O0[e] * c0 + O1[e] * c1) * inv;
    *(f32x4*)(orow + mf * 16 + grp * 4) = o;
  }
}

extern "C" void kernel_launch(void* const* d_in, const int* in_sizes, int n_in,
                              void* d_out, int out_size, void* d_ws, size_t ws_size,
                              hipStream_t stream) {
  const float* x  = (const float*)d_in[0];
  const float* Wq = (const float*)d_in[1];
  const float* Wk = (const float*)d_in[2];
  const float* Wv = (const float*)d_in[3];
  float* out = (float*)d_out;
  char* ws = (char*)d_ws;

  bf16_t* wt = (bf16_t*)(ws + WT_OFF);
  bf16_t* qb = (bf16_t*)(ws + Q_OFF);
  bf16_t* kb = (bf16_t*)(ws + K_OFF);
  bf16_t* vT = (bf16_t*)(ws + VT_OFF);

  hipLaunchKernelGGL(wt_kernel, dim3(48), dim3(256), 0, stream, Wq, Wk, Wv, wt);
  hipLaunchKernelGGL(proj_kernel, dim3(768), dim3(256), 0, stream, x, wt, qb, kb, vT);
  hipLaunchKernelGGL(attn_kernel, dim3(1024), dim3(128), 0, stream, qb, kb, vT, out);
}

// Round 8
// 120.948 us; speedup vs baseline: 1.0062x; 1.0062x over previous
//
#include <hip/hip_runtime.h>
#include <hip/hip_bf16.h>
#include <stdint.h>

typedef __bf16 bf16_t;
typedef __bf16 bf16x4 __attribute__((ext_vector_type(4)));
typedef __bf16 bf16x8 __attribute__((ext_vector_type(8)));
typedef float  f32x4  __attribute__((ext_vector_type(4)));

#define WAITVM(N) asm volatile("s_waitcnt vmcnt(" #N ")" ::: "memory")

// ---- workspace layout (bytes) ----
static constexpr size_t WT_OFF = 0;                    // Wt bf16 [384][1024] = 768 KB
static constexpr size_t Q_OFF  = (size_t)1 << 20;      // q bf16 [16384][128] = 4 MB (pre-scaled 1/32)
static constexpr size_t K_OFF  = Q_OFF + ((size_t)4 << 20);
static constexpr size_t VT_OFF = K_OFF + ((size_t)4 << 20);  // vT bf16 [8][128][2048] = 4 MB

__device__ __forceinline__ void g2lds16(const void* g, void* l) {
  __builtin_amdgcn_global_load_lds(
      (__attribute__((address_space(1))) void*)(g),
      (__attribute__((address_space(3))) void*)(l), 16, 0, 0);
}

// ---------------- W transpose: W[1024][128] fp32 -> Wt[384][1024] bf16 ----------------
__global__ __launch_bounds__(256) void wt_kernel(const float* __restrict__ Wq,
                                                 const float* __restrict__ Wk,
                                                 const float* __restrict__ Wv,
                                                 bf16_t* __restrict__ wt) {
  __shared__ float tile[64][129];
  int wi = blockIdx.x >> 4;   // 0..2
  int ct = blockIdx.x & 15;   // 0..15 -> c0
  const float* W = (wi == 0) ? Wq : ((wi == 1) ? Wk : Wv);
  int c0 = ct * 64;
  int tid = threadIdx.x;
  for (int i = 0; i < 32; ++i) {
    int idx = i * 256 + tid;
    int c = idx >> 7, n = idx & 127;
    tile[c][n] = W[(size_t)(c0 + c) * 128 + n];
  }
  __syncthreads();
  for (int i = 0; i < 32; ++i) {
    int idx = i * 256 + tid;
    int n = idx >> 6, c = idx & 63;
    wt[(size_t)(wi * 128 + n) * 1024 + c0 + c] = (bf16_t)tile[c][n];
  }
}

// ---------------- fused QKV projection v8: 2-wave t64xn128, wf register dbuf --------
// Grid 768 = 3 slices x 256 t-tiles(64), XCD-chunked. Block 128 thr = 2 waves (n-halves).
// Per BK=64 step: prefetch wf(ks+1) regs + stage x(ks+1) -> WAITVM(16) (drains exactly
// wf(ks)+stage(ks)) -> barrier -> 16 ds_read + cvt + 32 MFMA -> barrier. Loop hand-
// unrolled x2 so wfA/wfB and Blds[0]/[1] are static (rule 20).
__global__ __launch_bounds__(128) void proj_kernel(const float* __restrict__ x,
                                                   const bf16_t* __restrict__ wt,
                                                   bf16_t* __restrict__ q,
                                                   bf16_t* __restrict__ k,
                                                   bf16_t* __restrict__ vT) {
  __shared__ __align__(16) char Blds[2][16384];  // x tile [64 t][64 k] f32, 16B-chunk XOR swz

  int wgid = (blockIdx.x & 7) * 96 + (blockIdx.x >> 3);
  int t_tile = wgid / 3;
  int slice = wgid % 3;          // 0=Q, 1=K, 2=V
  int n0 = slice * 128;
  int t0 = t_tile * 64;

  int tid = threadIdx.x;
  int lane = tid & 63;
  int wave = tid >> 6;           // n-half
  int lq = lane & 15, grp = lane >> 4;

  const char* xb = (const char*)x;   // global row stride 4096 B

  f32x4 acc[4][4];
#pragma unroll
  for (int a = 0; a < 4; ++a)
#pragma unroll
    for (int s = 0; s < 4; ++s) acc[a][s] = (f32x4){0.f, 0.f, 0.f, 0.f};

  const bf16_t* wbase = wt + (size_t)(n0 + wave * 64 + lq) * 1024 + grp * 8;

  auto stageB = [&](int bi, int k0) {   // 8 x g2lds16
#pragma unroll
    for (int i = 0; i < 8; ++i) {
      int off = i * 2048 + tid * 16;
      int row = off >> 8;
      int c = (off >> 4) & 15;
      const char* src = xb + (size_t)(t0 + row) * 4096 + (size_t)k0 * 4
                        + ((c ^ (row & 15)) << 4);
      g2lds16(src, &Blds[bi][off]);
    }
  };

  bf16x8 wfA[4][2], wfB[4][2];
#define LOADW(DST, K0)                                                        \
  _Pragma("unroll") for (int kh = 0; kh < 2; ++kh)                            \
  _Pragma("unroll") for (int a = 0; a < 4; ++a)                               \
    DST[a][kh] = *(const bf16x8*)(wbase + (size_t)(a * 16) * 1024 + (K0) + kh * 32);

#define COMPUTE(BI, WF)                                                       \
  {                                                                           \
    bf16x8 xf[4][2];                                                          \
    _Pragma("unroll") for (int sub = 0; sub < 4; ++sub) {                     \
      int row = sub * 16 + lq;                                                \
      _Pragma("unroll") for (int kh = 0; kh < 2; ++kh) {                      \
        int c0 = kh * 8 + grp * 2;                                            \
        float4 f0 = *(const float4*)(&Blds[BI][row * 256 + (((c0)     ^ (row & 15)) << 4)]); \
        float4 f1 = *(const float4*)(&Blds[BI][row * 256 + (((c0 + 1) ^ (row & 15)) << 4)]); \
        bf16x8 v;                                                             \
        v[0] = (bf16_t)f0.x; v[1] = (bf16_t)f0.y; v[2] = (bf16_t)f0.z; v[3] = (bf16_t)f0.w; \
        v[4] = (bf16_t)f1.x; v[5] = (bf16_t)f1.y; v[6] = (bf16_t)f1.z; v[7] = (bf16_t)f1.w; \
        xf[sub][kh] = v;                                                      \
      }                                                                       \
    }                                                                         \
    _Pragma("unroll") for (int kh = 0; kh < 2; ++kh)                          \
    _Pragma("unroll") for (int a = 0; a < 4; ++a)                             \
    _Pragma("unroll") for (int sub = 0; sub < 4; ++sub)                       \
      acc[a][sub] = __builtin_amdgcn_mfma_f32_16x16x32_bf16(WF[a][kh], xf[sub][kh], \
                                                            acc[a][sub], 0, 0, 0); \
  }

  stageB(0, 0);
  LOADW(wfA, 0);

#pragma unroll 1
  for (int it = 0; it < 8; ++it) {
    int ksA = it * 2;
    // step A: compute (Blds[0], wfA); prefetch (Blds[1], wfB) for ksA+1
    LOADW(wfB, (ksA + 1) * 64);
    stageB(1, (ksA + 1) * 64);
    WAITVM(16);                      // drains wf(ksA)+stage(ksA)
    __builtin_amdgcn_s_barrier();
    __builtin_amdgcn_sched_barrier(0);
    COMPUTE(0, wfA);
    __builtin_amdgcn_s_barrier();

    // step B: compute (Blds[1], wfB); prefetch (Blds[0], wfA) for ksA+2
    if (it < 7) {
      LOADW(wfA, (ksA + 2) * 64);
      stageB(0, (ksA + 2) * 64);
      WAITVM(16);
    } else {
      WAITVM(0);
    }
    __builtin_amdgcn_s_barrier();
    __builtin_amdgcn_sched_barrier(0);
    COMPUTE(1, wfB);
    __builtin_amdgcn_s_barrier();
  }
#undef LOADW
#undef COMPUTE

  if (slice < 2) {   // Q (pre-scaled by 1/32) or K, row-major [t][128]
    bf16_t* dst = (slice == 0) ? q : k;
    float qs = (slice == 0) ? 0.03125f : 1.0f;   // fold C^-0.5 into Q (exact in bf16)
#pragma unroll
    for (int a = 0; a < 4; ++a)
#pragma unroll
      for (int sub = 0; sub < 4; ++sub) {
        bf16x4 o;
        o[0] = (bf16_t)(acc[a][sub][0] * qs); o[1] = (bf16_t)(acc[a][sub][1] * qs);
        o[2] = (bf16_t)(acc[a][sub][2] * qs); o[3] = (bf16_t)(acc[a][sub][3] * qs);
        *(bf16x4*)(dst + (size_t)(t0 + sub * 16 + lq) * 128 + wave * 64 + a * 16 + grp * 4) = o;
      }
  } else {           // V transposed: vT[b][d][t]
    int b = t0 >> 11;
#pragma unroll
    for (int a = 0; a < 4; ++a)
#pragma unroll
      for (int sub = 0; sub < 4; ++sub) {
        int tt = (t0 + sub * 16 + lq) & 2047;
#pragma unroll
        for (int r = 0; r < 4; ++r) {
          int d = wave * 64 + a * 16 + grp * 4 + r;
          vT[(size_t)b * 128 * 2048 + (size_t)d * 2048 + tt] = (bf16_t)acc[a][sub][r];
        }
      }
  }
}

// ---------------- flash attention v8: kv-split-4, oversubscribed grid, no barriers --
// 1024 blocks = 8 b (XCD-pinned) x 128 q-tiles(16 rows), heavy-first; 4 waves/block.
// LDS 68K -> 2 blocks/CU resident -> grid is 2x capacity -> HW backfills retired
// blocks (dynamic balance). Wave w: kv tiles {w, w+4, ...} of 32, private K dbuf
// (g2lds), V->regs one tile ahead, counted vmcnt, zero loop barriers. 4-way merge.
__global__ __launch_bounds__(256) void attn_kernel(const bf16_t* __restrict__ q,
                                                   const bf16_t* __restrict__ k,
                                                   const bf16_t* __restrict__ vT,
                                                   float* __restrict__ out) {
  __shared__ __align__(16) char lds[69632];  // w*16K: K dbuf 2x8K | 65536+w*1K: P

  int tid = threadIdx.x;
  int lane = tid & 63;
  int w = tid >> 6;                  // kv-split index 0..3
  int lq = lane & 15, grp = lane >> 4;
  int b = blockIdx.x & 7;            // XCD-pinned batch
  int qt = 127 - (blockIdx.x >> 3);  // heavy (long prefix) first; 16 q-rows
  int tq = qt * 16 + lq;

  bf16x8 qf[4];
  const bf16_t* qrow = q + ((size_t)b * 2048 + tq) * 128 + grp * 8;
#pragma unroll
  for (int ks = 0; ks < 4; ++ks) qf[ks] = *(const bf16x8*)(qrow + ks * 32);

  float mrun = -__builtin_inff();
  float lsum = 0.f;
  f32x4 accO[8];
#pragma unroll
  for (int i = 0; i < 8; ++i) accO[i] = (f32x4){0.f, 0.f, 0.f, 0.f};

  const char* kbase = (const char*)(k + (size_t)b * 2048 * 128);
  const bf16_t* vb = vT + (size_t)b * 128 * 2048;

  auto stageK = [&](int bi, int kv0) {   // 8K tile [32 kv][256B], per-wave private
#pragma unroll
    for (int i = 0; i < 8; ++i) {
      int off = i * 1024 + lane * 16;
      int row = off >> 8;
      int c = (off >> 4) & 15;
      const char* src = kbase + (size_t)(kv0 + row) * 256 + ((c ^ (row & 7)) << 4);
      g2lds16(src, &lds[w * 16384 + bi * 8192 + off]);
    }
  };

  bf16x8 vf[8];
  auto loadV = [&](int kv0) {            // V^T frags direct to regs (8 vm)
#pragma unroll
    for (int mf = 0; mf < 8; ++mf)
      vf[mf] = *(const bf16x8*)(vb + (size_t)(mf * 16 + lq) * 2048 + kv0 + grp * 8);
  };

  int nt = (qt >> 1) + 1;                // kv tiles of 32 covering [0, qt*16+16)
  int cnt = (nt - w + 3) >> 2;           // tiles w, w+4, ... below nt

  if (cnt > 0) { stageK(0, w * 32); loadV(w * 32); }

  for (int i = 0; i < cnt; ++i) {
    int kv0 = (w + 4 * i) * 32;
    int cur = i & 1;
    bool pre = (i + 1 < cnt);
    if (pre) { stageK(cur ^ 1, kv0 + 128); WAITVM(16); }  // K(i) ready; K(i+1)+V(i) fly
    else     { WAITVM(8); }                               // K(i) ready; V(i) flies
    __builtin_amdgcn_sched_barrier(0);

    // S^T = K · Q^T : [32 kv][16 q]  (Q pre-scaled by 1/32)
    f32x4 s[2];
    s[0] = (f32x4){0.f, 0.f, 0.f, 0.f};
    s[1] = (f32x4){0.f, 0.f, 0.f, 0.f};
#pragma unroll
    for (int ks = 0; ks < 4; ++ks) {
#pragma unroll
      for (int mf = 0; mf < 2; ++mf) {
        int row = mf * 16 + lq;
        bf16x8 kf = *(const bf16x8*)(&lds[w * 16384 + cur * 8192 + row * 256
                                          + (((ks * 4 + grp) ^ (row & 7)) << 4)]);
        s[mf] = __builtin_amdgcn_mfma_f32_16x16x32_bf16(kf, qf[ks], s[mf], 0, 0, 0);
      }
    }

    // online softmax; lane owns q-row tq, holds 8 kv values
    float z[2][4];
    float pmax = -__builtin_inff();
    bool hasmask = (kv0 + 31 > qt * 16);   // wave-uniform: only diagonal-ish tiles mask
    if (hasmask) {
#pragma unroll
      for (int f = 0; f < 2; ++f)
#pragma unroll
        for (int r = 0; r < 4; ++r) {
          int kv = kv0 + f * 16 + grp * 4 + r;
          float zz = (kv <= tq) ? s[f][r] : -__builtin_inff();
          z[f][r] = zz;
          pmax = fmaxf(pmax, zz);
        }
    } else {
#pragma unroll
      for (int f = 0; f < 2; ++f)
#pragma unroll
        for (int r = 0; r < 4; ++r) {
          z[f][r] = s[f][r];
          pmax = fmaxf(pmax, s[f][r]);
        }
    }
    pmax = fmaxf(pmax, __shfl_xor(pmax, 16, 64));
    pmax = fmaxf(pmax, __shfl_xor(pmax, 32, 64));

    float p[2][4];
    float psum = 0.f;
    if (__all(pmax <= mrun)) {           // defer-rescale: max didn't grow anywhere
#pragma unroll
      for (int f = 0; f < 2; ++f)
#pragma unroll
        for (int r = 0; r < 4; ++r) {
          p[f][r] = __expf(z[f][r] - mrun);
          psum += p[f][r];
        }
      psum += __shfl_xor(psum, 16, 64);
      psum += __shfl_xor(psum, 32, 64);
      lsum += psum;
    } else {
      float mnew = fmaxf(mrun, pmax);
      float msub = fmaxf(mnew, -3e38f);  // NaN guard (fully-masked lanes impossible tile 0)
      float corr = __expf(mrun - msub);
#pragma unroll
      for (int f = 0; f < 2; ++f)
#pragma unroll
        for (int r = 0; r < 4; ++r) {
          p[f][r] = __expf(z[f][r] - msub);
          psum += p[f][r];
        }
      psum += __shfl_xor(psum, 16, 64);
      psum += __shfl_xor(psum, 32, 64);
      lsum = lsum * corr + psum;
      mrun = mnew;
#pragma unroll
      for (int i2 = 0; i2 < 8; ++i2) accO[i2] *= corr;
    }

    // pack P^T (wave-private 1KB region; intra-wave lgkm ordering)
#pragma unroll
    for (int f = 0; f < 2; ++f) {
      bf16x4 pw;
      pw[0] = (bf16_t)p[f][0]; pw[1] = (bf16_t)p[f][1];
      pw[2] = (bf16_t)p[f][2]; pw[3] = (bf16_t)p[f][3];
      *(bf16x4*)(&lds[65536 + w * 1024 + ((f * 2 + (grp >> 1)) << 8)
                      + lq * 16 + ((grp & 1) << 3)]) = pw;
    }

    if (pre) { WAITVM(8); }   // V(i) regs ready; K(i+1) stays in flight
    else     { WAITVM(0); }
    __builtin_amdgcn_sched_barrier(0);

    // O^T += V^T · P^T (V in regs, single k-step of 32)
    bf16x8 pf = *(const bf16x8*)(&lds[65536 + w * 1024 + (grp << 8) + lq * 16]);
#pragma unroll
    for (int mf = 0; mf < 8; ++mf)
      accO[mf] = __builtin_amdgcn_mfma_f32_16x16x32_bf16(vf[mf], pf, accO[mf], 0, 0, 0);

    if (pre) loadV(kv0 + 128);  // next V after PV consumed vf (in-order WAR-safe)
  }

  // ---- 4-way kv-split merge via LDS (single barrier) ----
#pragma unroll
  for (int mf = 0; mf < 8; ++mf)
    *(f32x4*)(&lds[w * 16384 + lane * 128 + mf * 16]) = accO[mf];
  *(float*)(&lds[w * 16384 + 8192 + lane * 8])     = mrun;
  *(float*)(&lds[w * 16384 + 8192 + lane * 8 + 4]) = lsum;
  __syncthreads();

  float mm[4], ll[4];
#pragma unroll
  for (int u = 0; u < 4; ++u) {
    mm[u] = *(const float*)(&lds[u * 16384 + 8192 + lane * 8]);
    ll[u] = *(const float*)(&lds[u * 16384 + 8192 + lane * 8 + 4]);
  }
  float m = fmaxf(fmaxf(mm[0], mm[1]), fmaxf(mm[2], mm[3]));
  float cc[4], L = 0.f;
#pragma unroll
  for (int u = 0; u < 4; ++u) { cc[u] = __expf(mm[u] - m); L += ll[u] * cc[u]; }
  float inv = 1.0f / L;
  float* orow = out + ((size_t)b * 2048 + tq) * 128;
#pragma unroll
  for (int j = 0; j < 2; ++j) {
    int mf = w * 2 + j;
    f32x4 o = (f32x4){0.f, 0.f, 0.f, 0.f};
#pragma unroll
    for (int u = 0; u < 4; ++u) {
      f32x4 Ou = *(const f32x4*)(&lds[u * 16384 + lane * 128 + mf * 16]);
#pragma unroll
      for (int e = 0; e < 4; ++e) o[e] += Ou[e] * cc[u];
    }
#pragma unroll
    for (int e = 0; e < 4; ++e) o[e] *= inv;
    *(f32x4*)(orow + mf * 16 + grp * 4) = o;
  }
}

extern "C" void kernel_launch(void* const* d_in, const int* in_sizes, int n_in,
                              void* d_out, int out_size, void* d_ws, size_t ws_size,
                              hipStream_t stream) {
  const float* x  = (const float*)d_in[0];
  const float* Wq = (const float*)d_in[1];
  const float* Wk = (const float*)d_in[2];
  const float* Wv = (const float*)d_in[3];
  float* out = (float*)d_out;
  char* ws = (char*)d_ws;

  bf16_t* wt = (bf16_t*)(ws + WT_OFF);
  bf16_t* qb = (bf16_t*)(ws + Q_OFF);
  bf16_t* kb = (bf16_t*)(ws + K_OFF);
  bf16_t* vT = (bf16_t*)(ws + VT_OFF);

  hipLaunchKernelGGL(wt_kernel, dim3(48), dim3(256), 0, stream, Wq, Wk, Wv, wt);
  hipLaunchKernelGGL(proj_kernel, dim3(768), dim3(128), 0, stream, x, wt, qb, kb, vT);
  hipLaunchKernelGGL(attn_kernel, dim3(1024), dim3(256), 0, stream, qb, kb, vT, out);
}

// Round 9
// 106.880 us; speedup vs baseline: 1.1386x; 1.1316x over previous
//
#include <hip/hip_runtime.h>
#include <hip/hip_bf16.h>
#include <stdint.h>

typedef __bf16 bf16_t;
typedef __bf16 bf16x4 __attribute__((ext_vector_type(4)));
typedef __bf16 bf16x8 __attribute__((ext_vector_type(8)));
typedef float  f32x4  __attribute__((ext_vector_type(4)));

#define WAITVM(N) asm volatile("s_waitcnt vmcnt(" #N ")" ::: "memory")

// ---- workspace layout (bytes) ----
static constexpr size_t WT_OFF = 0;                    // Wt bf16 [384][1024] = 768 KB
static constexpr size_t Q_OFF  = (size_t)1 << 20;      // q bf16 (pre-scaled 1/32) 4 MB
static constexpr size_t K_OFF  = Q_OFF + ((size_t)4 << 20);
static constexpr size_t VT_OFF = K_OFF + ((size_t)4 << 20);  // vT bf16 [8][128][2048] = 4 MB

__device__ __forceinline__ void g2lds16(const void* g, void* l) {
  __builtin_amdgcn_global_load_lds(
      (__attribute__((address_space(1))) void*)(g),
      (__attribute__((address_space(3))) void*)(l), 16, 0, 0);
}

// ---------------- W transpose: W[1024][128] fp32 -> Wt[384][1024] bf16 ----------------
__global__ __launch_bounds__(256) void wt_kernel(const float* __restrict__ Wq,
                                                 const float* __restrict__ Wk,
                                                 const float* __restrict__ Wv,
                                                 bf16_t* __restrict__ wt) {
  __shared__ float tile[64][129];
  int wi = blockIdx.x >> 4;
  int ct = blockIdx.x & 15;
  const float* W = (wi == 0) ? Wq : ((wi == 1) ? Wk : Wv);
  int c0 = ct * 64;
  int tid = threadIdx.x;
  for (int i = 0; i < 32; ++i) {
    int idx = i * 256 + tid;
    int c = idx >> 7, n = idx & 127;
    tile[c][n] = W[(size_t)(c0 + c) * 128 + n];
  }
  __syncthreads();
  for (int i = 0; i < 32; ++i) {
    int idx = i * 256 + tid;
    int n = idx >> 6, c = idx & 63;
    wt[(size_t)(wi * 128 + n) * 1024 + c0 + c] = (bf16_t)tile[c][n];
  }
}

// ---------------- fused QKV projection v6 (reverted: measured ~33us) + Q prescale ---
// Grid 768 = 3 slices x 256 t-tiles(64), XCD-chunked. Block 128 thr = 2 waves.
__global__ __launch_bounds__(128) void proj_kernel(const float* __restrict__ x,
                                                   const bf16_t* __restrict__ wt,
                                                   bf16_t* __restrict__ q,
                                                   bf16_t* __restrict__ k,
                                                   bf16_t* __restrict__ vT) {
  __shared__ __align__(16) char Blds[2][16384];  // x tile [64 t][64 k] f32, 16B-chunk XOR swz

  int wgid = (blockIdx.x & 7) * 96 + (blockIdx.x >> 3);
  int t_tile = wgid / 3;
  int slice = wgid % 3;          // 0=Q, 1=K, 2=V
  int n0 = slice * 128;
  int t0 = t_tile * 64;

  int tid = threadIdx.x;
  int lane = tid & 63;
  int wave = tid >> 6;           // n-half
  int lq = lane & 15, grp = lane >> 4;

  const char* xb = (const char*)x;   // global row stride 4096 B

  f32x4 acc[4][4];
#pragma unroll
  for (int a = 0; a < 4; ++a)
#pragma unroll
    for (int s = 0; s < 4; ++s) acc[a][s] = (f32x4){0.f, 0.f, 0.f, 0.f};

  const bf16_t* wbase = wt + (size_t)(n0 + wave * 64 + lq) * 1024 + grp * 8;

  auto stageB = [&](int bi, int k0) {
#pragma unroll
    for (int i = 0; i < 8; ++i) {
      int off = i * 2048 + tid * 16;
      int row = off >> 8;
      int c = (off >> 4) & 15;
      const char* src = xb + (size_t)(t0 + row) * 4096 + (size_t)k0 * 4
                        + ((c ^ (row & 15)) << 4);
      g2lds16(src, &Blds[bi][off]);
    }
  };

  stageB(0, 0);

  for (int ks = 0; ks < 16; ++ks) {
    int cur = ks & 1;
    int k0 = ks * 64;

    bf16x8 wf[4][2];
#pragma unroll
    for (int kh = 0; kh < 2; ++kh)
#pragma unroll
      for (int a = 0; a < 4; ++a)
        wf[a][kh] = *(const bf16x8*)(wbase + (size_t)(a * 16) * 1024 + k0 + kh * 32);

    if (ks < 15) {
      stageB(cur ^ 1, (ks + 1) * 64);
      WAITVM(16);              // drains stage(ks); wf(ks)+stage(ks+1) may stay in flight
    } else {
      WAITVM(8);
    }
    __builtin_amdgcn_s_barrier();
    __builtin_amdgcn_sched_barrier(0);

    bf16x8 xf[4][2];
#pragma unroll
    for (int sub = 0; sub < 4; ++sub) {
      int row = sub * 16 + lq;
#pragma unroll
      for (int kh = 0; kh < 2; ++kh) {
        int c0 = kh * 8 + grp * 2;
        float4 f0 = *(const float4*)(&Blds[cur][row * 256 + (((c0)     ^ (row & 15)) << 4)]);
        float4 f1 = *(const float4*)(&Blds[cur][row * 256 + (((c0 + 1) ^ (row & 15)) << 4)]);
        bf16x8 v;
        v[0] = (bf16_t)f0.x; v[1] = (bf16_t)f0.y; v[2] = (bf16_t)f0.z; v[3] = (bf16_t)f0.w;
        v[4] = (bf16_t)f1.x; v[5] = (bf16_t)f1.y; v[6] = (bf16_t)f1.z; v[7] = (bf16_t)f1.w;
        xf[sub][kh] = v;
      }
    }

#pragma unroll
    for (int kh = 0; kh < 2; ++kh)
#pragma unroll
      for (int a = 0; a < 4; ++a)
#pragma unroll
        for (int sub = 0; sub < 4; ++sub)
          acc[a][sub] = __builtin_amdgcn_mfma_f32_16x16x32_bf16(wf[a][kh], xf[sub][kh],
                                                                acc[a][sub], 0, 0, 0);
    __builtin_amdgcn_s_barrier();
  }

  if (slice < 2) {   // Q (pre-scaled 1/32, exact in bf16) or K, row-major [t][128]
    bf16_t* dst = (slice == 0) ? q : k;
    float qs = (slice == 0) ? 0.03125f : 1.0f;
#pragma unroll
    for (int a = 0; a < 4; ++a)
#pragma unroll
      for (int sub = 0; sub < 4; ++sub) {
        bf16x4 o;
        o[0] = (bf16_t)(acc[a][sub][0] * qs); o[1] = (bf16_t)(acc[a][sub][1] * qs);
        o[2] = (bf16_t)(acc[a][sub][2] * qs); o[3] = (bf16_t)(acc[a][sub][3] * qs);
        *(bf16x4*)(dst + (size_t)(t0 + sub * 16 + lq) * 128 + wave * 64 + a * 16 + grp * 4) = o;
      }
  } else {           // V transposed: vT[b][d][t]
    int b = t0 >> 11;
#pragma unroll
    for (int a = 0; a < 4; ++a)
#pragma unroll
      for (int sub = 0; sub < 4; ++sub) {
        int tt = (t0 + sub * 16 + lq) & 2047;
#pragma unroll
        for (int r = 0; r < 4; ++r) {
          int d = wave * 64 + a * 16 + grp * 4 + r;
          vT[(size_t)b * 128 * 2048 + (size_t)d * 2048 + tt] = (bf16_t)acc[a][sub][r];
        }
      }
  }
}

// ---------------- flash attention v9: kv-split-4, 36KB LDS, 3 waves/SIMD ------------
// 1024 blocks = 8 b (XCD-pinned) x 128 q-tiles(16 rows), heavy-first; 4 waves/block.
// Per wave: K single-buf LDS (8KB, prefetched 1 tile ahead), V single-buf regs
// (prefetched 1 tile ahead), counted per-wave vmcnt, zero loop barriers.
// vm queue invariant entering iter i: [stageK(i) 8, loadV(i) 8].
__global__ __launch_bounds__(256, 3) void attn_kernel(const bf16_t* __restrict__ q,
                                                      const bf16_t* __restrict__ k,
                                                      const bf16_t* __restrict__ vT,
                                                      float* __restrict__ out) {
  __shared__ __align__(16) char lds[36864];  // w*8K: K buf (merge: O dump) | 32768+w*1K: P (merge: m/l)

  int tid = threadIdx.x;
  int lane = tid & 63;
  int w = tid >> 6;                  // kv-split index 0..3
  int lq = lane & 15, grp = lane >> 4;
  int b = blockIdx.x & 7;            // XCD-pinned batch
  int qt = 127 - (blockIdx.x >> 3);  // heavy first; 16 q-rows
  int tq = qt * 16 + lq;

  bf16x8 qf[4];
  const bf16_t* qrow = q + ((size_t)b * 2048 + tq) * 128 + grp * 8;
#pragma unroll
  for (int ks = 0; ks < 4; ++ks) qf[ks] = *(const bf16x8*)(qrow + ks * 32);

  float mrun = -__builtin_inff();
  float lsum = 0.f;
  f32x4 accO[8];
#pragma unroll
  for (int i = 0; i < 8; ++i) accO[i] = (f32x4){0.f, 0.f, 0.f, 0.f};

  const char* kbase = (const char*)(k + (size_t)b * 2048 * 128);
  const bf16_t* vb = vT + (size_t)b * 128 * 2048;

  auto stageK = [&](int kv0) {   // 8KB tile [32 kv][256B], per-wave private, XOR swz
#pragma unroll
    for (int i = 0; i < 8; ++i) {
      int off = i * 1024 + lane * 16;
      int row = off >> 8;
      int c = (off >> 4) & 15;
      const char* src = kbase + (size_t)(kv0 + row) * 256 + ((c ^ (row & 7)) << 4);
      g2lds16(src, &lds[w * 8192 + off]);
    }
  };

  bf16x8 vf[8];
  auto loadV = [&](int kv0) {    // V^T frags direct to regs (8 x 16B)
#pragma unroll
    for (int mf = 0; mf < 8; ++mf)
      vf[mf] = *(const bf16x8*)(vb + (size_t)(mf * 16 + lq) * 2048 + kv0 + grp * 8);
  };

  int nt = (qt >> 1) + 1;            // kv tiles of 32 covering [0, qt*16+16)
  int cnt = (nt - w + 3) >> 2;       // tiles w, w+4, ...

  if (cnt > 0) { stageK(w * 32); loadV(w * 32); }

#pragma unroll 1
  for (int i = 0; i < cnt; ++i) {
    int kv0 = (w + 4 * i) * 32;
    bool pre = (i + 1 < cnt);

    WAITVM(8);                       // K(i) landed; V(i) still in flight
    __builtin_amdgcn_sched_barrier(0);

    // kf from LDS, then free the buffer for stage(i+1)
    bf16x8 kf[4][2];
#pragma unroll
    for (int ks = 0; ks < 4; ++ks)
#pragma unroll
      for (int mf = 0; mf < 2; ++mf) {
        int row = mf * 16 + lq;
        kf[ks][mf] = *(const bf16x8*)(&lds[w * 8192 + row * 256
                                           + (((ks * 4 + grp) ^ (row & 7)) << 4)]);
      }
    asm volatile("s_waitcnt lgkmcnt(0)" ::: "memory");
    __builtin_amdgcn_sched_barrier(0);
    if (pre) stageK(kv0 + 128);      // overwrite own buffer (reads done)

    // S^T = K · Q^T (Q pre-scaled by 1/32)
    f32x4 s[2];
    s[0] = (f32x4){0.f, 0.f, 0.f, 0.f};
    s[1] = (f32x4){0.f, 0.f, 0.f, 0.f};
#pragma unroll
    for (int ks = 0; ks < 4; ++ks)
#pragma unroll
      for (int mf = 0; mf < 2; ++mf)
        s[mf] = __builtin_amdgcn_mfma_f32_16x16x32_bf16(kf[ks][mf], qf[ks], s[mf], 0, 0, 0);

    // online softmax in-place in s; lane owns q-row tq, holds 8 kv values
    bool hasmask = (kv0 + 31 > qt * 16);
    if (hasmask) {
#pragma unroll
      for (int f = 0; f < 2; ++f)
#pragma unroll
        for (int r = 0; r < 4; ++r) {
          int kv = kv0 + f * 16 + grp * 4 + r;
          s[f][r] = (kv <= tq) ? s[f][r] : -__builtin_inff();
        }
    }
    float pmax = -__builtin_inff();
#pragma unroll
    for (int f = 0; f < 2; ++f)
#pragma unroll
      for (int r = 0; r < 4; ++r) pmax = fmaxf(pmax, s[f][r]);
    pmax = fmaxf(pmax, __shfl_xor(pmax, 16, 64));
    pmax = fmaxf(pmax, __shfl_xor(pmax, 32, 64));

    float msub;
    if (__all(pmax <= mrun)) {       // defer-rescale
      msub = mrun;
    } else {
      float mnew = fmaxf(mrun, pmax);
      msub = fmaxf(mnew, -3e38f);    // NaN guard
      float corr = __expf(mrun - msub);
      lsum *= corr;
      mrun = mnew;
#pragma unroll
      for (int i2 = 0; i2 < 8; ++i2) accO[i2] *= corr;
    }

    // fused exp + bf16 pack + psum  (P^T into wave-private 1KB)
    float psum = 0.f;
#pragma unroll
    for (int f = 0; f < 2; ++f) {
      bf16x4 pw;
#pragma unroll
      for (int r = 0; r < 4; ++r) {
        float pe = __expf(s[f][r] - msub);
        psum += pe;
        pw[r] = (bf16_t)pe;
      }
      *(bf16x4*)(&lds[32768 + w * 1024 + ((f * 2 + (grp >> 1)) << 8)
                      + lq * 16 + ((grp & 1) << 3)]) = pw;
    }
    psum += __shfl_xor(psum, 16, 64);
    psum += __shfl_xor(psum, 32, 64);
    lsum += psum;

    if (pre) { WAITVM(8); }          // V(i) regs ready; K(i+1) stays in flight
    else     { WAITVM(0); }
    __builtin_amdgcn_sched_barrier(0);

    // O^T += V^T · P^T
    bf16x8 pf = *(const bf16x8*)(&lds[32768 + w * 1024 + (grp << 8) + lq * 16]);
#pragma unroll
    for (int mf = 0; mf < 8; ++mf)
      accO[mf] = __builtin_amdgcn_mfma_f32_16x16x32_bf16(vf[mf], pf, accO[mf], 0, 0, 0);

    if (pre) loadV(kv0 + 128);       // next V after PV consumed vf
  }

  // ---- 4-way kv-split merge via LDS (single barrier); K/P regions reused ----
#pragma unroll
  for (int mf = 0; mf < 8; ++mf)
    *(f32x4*)(&lds[w * 8192 + lane * 128 + mf * 16]) = accO[mf];
  *(float*)(&lds[32768 + w * 1024 + lane * 8])     = mrun;
  *(float*)(&lds[32768 + w * 1024 + lane * 8 + 4]) = lsum;
  __syncthreads();

  float mm[4], ll[4];
#pragma unroll
  for (int u = 0; u < 4; ++u) {
    mm[u] = *(const float*)(&lds[32768 + u * 1024 + lane * 8]);
    ll[u] = *(const float*)(&lds[32768 + u * 1024 + lane * 8 + 4]);
  }
  float m = fmaxf(fmaxf(mm[0], mm[1]), fmaxf(mm[2], mm[3]));
  float cc[4], L = 0.f;
#pragma unroll
  for (int u = 0; u < 4; ++u) { cc[u] = __expf(mm[u] - m); L += ll[u] * cc[u]; }
  float inv = 1.0f / L;
  float* orow = out + ((size_t)b * 2048 + tq) * 128;
#pragma unroll
  for (int j = 0; j < 2; ++j) {
    int mf = w * 2 + j;
    f32x4 o = (f32x4){0.f, 0.f, 0.f, 0.f};
#pragma unroll
    for (int u = 0; u < 4; ++u) {
      f32x4 Ou = *(const f32x4*)(&lds[u * 8192 + lane * 128 + mf * 16]);
#pragma unroll
      for (int e = 0; e < 4; ++e) o[e] += Ou[e] * cc[u];
    }
#pragma unroll
    for (int e = 0; e < 4; ++e) o[e] *= inv;
    *(f32x4*)(orow + mf * 16 + grp * 4) = o;
  }
}

extern "C" void kernel_launch(void* const* d_in, const int* in_sizes, int n_in,
                              void* d_out, int out_size, void* d_ws, size_t ws_size,
                              hipStream_t stream) {
  const float* x  = (const float*)d_in[0];
  const float* Wq = (const float*)d_in[1];
  const float* Wk = (const float*)d_in[2];
  const float* Wv = (const float*)d_in[3];
  float* out = (float*)d_out;
  char* ws = (char*)d_ws;

  bf16_t* wt = (bf16_t*)(ws + WT_OFF);
  bf16_t* qb = (bf16_t*)(ws + Q_OFF);
  bf16_t* kb = (bf16_t*)(ws + K_OFF);
  bf16_t* vT = (bf16_t*)(ws + VT_OFF);

  hipLaunchKernelGGL(wt_kernel, dim3(48), dim3(256), 0, stream, Wq, Wk, Wv, wt);
  hipLaunchKernelGGL(proj_kernel, dim3(768), dim3(128), 0, stream, x, wt, qb, kb, vT);
  hipLaunchKernelGGL(attn_kernel, dim3(1024), dim3(256), 0, stream, qb, kb, vT, out);
}

// Round 10
// 96.657 us; speedup vs baseline: 1.2591x; 1.1058x over previous
//
#include <hip/hip_runtime.h>
#include <hip/hip_bf16.h>
#include <stdint.h>

typedef __bf16 bf16_t;
typedef __bf16 bf16x4 __attribute__((ext_vector_type(4)));
typedef __bf16 bf16x8 __attribute__((ext_vector_type(8)));
typedef float  f32x4  __attribute__((ext_vector_type(4)));

#define WAITVM(N) asm volatile("s_waitcnt vmcnt(" #N ")" ::: "memory")

// ---- workspace layout (bytes) ----
static constexpr size_t WT_OFF = 0;                    // Wt bf16 [384][1024] = 768 KB
static constexpr size_t Q_OFF  = (size_t)1 << 20;      // q bf16 (pre-scaled 1/32) 4 MB
static constexpr size_t K_OFF  = Q_OFF + ((size_t)4 << 20);
static constexpr size_t VT_OFF = K_OFF + ((size_t)4 << 20);  // vT bf16 [8][128][2048] = 4 MB

__device__ __forceinline__ void g2lds16(const void* g, void* l) {
  __builtin_amdgcn_global_load_lds(
      (__attribute__((address_space(1))) void*)(g),
      (__attribute__((address_space(3))) void*)(l), 16, 0, 0);
}

// ---------------- W transpose: W[1024][128] fp32 -> Wt[384][1024] bf16 ----------------
__global__ __launch_bounds__(256) void wt_kernel(const float* __restrict__ Wq,
                                                 const float* __restrict__ Wk,
                                                 const float* __restrict__ Wv,
                                                 bf16_t* __restrict__ wt) {
  __shared__ float tile[64][129];
  int wi = blockIdx.x >> 4;
  int ct = blockIdx.x & 15;
  const float* W = (wi == 0) ? Wq : ((wi == 1) ? Wk : Wv);
  int c0 = ct * 64;
  int tid = threadIdx.x;
  for (int i = 0; i < 32; ++i) {
    int idx = i * 256 + tid;
    int c = idx >> 7, n = idx & 127;
    tile[c][n] = W[(size_t)(c0 + c) * 128 + n];
  }
  __syncthreads();
  for (int i = 0; i < 32; ++i) {
    int idx = i * 256 + tid;
    int n = idx >> 6, c = idx & 63;
    wt[(size_t)(wi * 128 + n) * 1024 + c0 + c] = (bf16_t)tile[c][n];
  }
}

// ---------------- fused QKV projection v6 (measured ~33us) + Q prescale -------------
// Grid 768 = 3 slices x 256 t-tiles(64), XCD-chunked. Block 128 thr = 2 waves.
__global__ __launch_bounds__(128) void proj_kernel(const float* __restrict__ x,
                                                   const bf16_t* __restrict__ wt,
                                                   bf16_t* __restrict__ q,
                                                   bf16_t* __restrict__ k,
                                                   bf16_t* __restrict__ vT) {
  __shared__ __align__(16) char Blds[2][16384];  // x tile [64 t][64 k] f32, 16B-chunk XOR swz

  int wgid = (blockIdx.x & 7) * 96 + (blockIdx.x >> 3);
  int t_tile = wgid / 3;
  int slice = wgid % 3;          // 0=Q, 1=K, 2=V
  int n0 = slice * 128;
  int t0 = t_tile * 64;

  int tid = threadIdx.x;
  int lane = tid & 63;
  int wave = tid >> 6;           // n-half
  int lq = lane & 15, grp = lane >> 4;

  const char* xb = (const char*)x;   // global row stride 4096 B

  f32x4 acc[4][4];
#pragma unroll
  for (int a = 0; a < 4; ++a)
#pragma unroll
    for (int s = 0; s < 4; ++s) acc[a][s] = (f32x4){0.f, 0.f, 0.f, 0.f};

  const bf16_t* wbase = wt + (size_t)(n0 + wave * 64 + lq) * 1024 + grp * 8;

  auto stageB = [&](int bi, int k0) {
#pragma unroll
    for (int i = 0; i < 8; ++i) {
      int off = i * 2048 + tid * 16;
      int row = off >> 8;
      int c = (off >> 4) & 15;
      const char* src = xb + (size_t)(t0 + row) * 4096 + (size_t)k0 * 4
                        + ((c ^ (row & 15)) << 4);
      g2lds16(src, &Blds[bi][off]);
    }
  };

  stageB(0, 0);

  for (int ks = 0; ks < 16; ++ks) {
    int cur = ks & 1;
    int k0 = ks * 64;

    bf16x8 wf[4][2];
#pragma unroll
    for (int kh = 0; kh < 2; ++kh)
#pragma unroll
      for (int a = 0; a < 4; ++a)
        wf[a][kh] = *(const bf16x8*)(wbase + (size_t)(a * 16) * 1024 + k0 + kh * 32);

    if (ks < 15) {
      stageB(cur ^ 1, (ks + 1) * 64);
      WAITVM(16);              // drains stage(ks); wf(ks)+stage(ks+1) may stay in flight
    } else {
      WAITVM(8);
    }
    __builtin_amdgcn_s_barrier();
    __builtin_amdgcn_sched_barrier(0);

    bf16x8 xf[4][2];
#pragma unroll
    for (int sub = 0; sub < 4; ++sub) {
      int row = sub * 16 + lq;
#pragma unroll
      for (int kh = 0; kh < 2; ++kh) {
        int c0 = kh * 8 + grp * 2;
        float4 f0 = *(const float4*)(&Blds[cur][row * 256 + (((c0)     ^ (row & 15)) << 4)]);
        float4 f1 = *(const float4*)(&Blds[cur][row * 256 + (((c0 + 1) ^ (row & 15)) << 4)]);
        bf16x8 v;
        v[0] = (bf16_t)f0.x; v[1] = (bf16_t)f0.y; v[2] = (bf16_t)f0.z; v[3] = (bf16_t)f0.w;
        v[4] = (bf16_t)f1.x; v[5] = (bf16_t)f1.y; v[6] = (bf16_t)f1.z; v[7] = (bf16_t)f1.w;
        xf[sub][kh] = v;
      }
    }

#pragma unroll
    for (int kh = 0; kh < 2; ++kh)
#pragma unroll
      for (int a = 0; a < 4; ++a)
#pragma unroll
        for (int sub = 0; sub < 4; ++sub)
          acc[a][sub] = __builtin_amdgcn_mfma_f32_16x16x32_bf16(wf[a][kh], xf[sub][kh],
                                                                acc[a][sub], 0, 0, 0);
    __builtin_amdgcn_s_barrier();
  }

  if (slice < 2) {   // Q (pre-scaled 1/32, exact in bf16) or K, row-major [t][128]
    bf16_t* dst = (slice == 0) ? q : k;
    float qs = (slice == 0) ? 0.03125f : 1.0f;
#pragma unroll
    for (int a = 0; a < 4; ++a)
#pragma unroll
      for (int sub = 0; sub < 4; ++sub) {
        bf16x4 o;
        o[0] = (bf16_t)(acc[a][sub][0] * qs); o[1] = (bf16_t)(acc[a][sub][1] * qs);
        o[2] = (bf16_t)(acc[a][sub][2] * qs); o[3] = (bf16_t)(acc[a][sub][3] * qs);
        *(bf16x4*)(dst + (size_t)(t0 + sub * 16 + lq) * 128 + wave * 64 + a * 16 + grp * 4) = o;
      }
  } else {           // V transposed: vT[b][d][t]
    int b = t0 >> 11;
#pragma unroll
    for (int a = 0; a < 4; ++a)
#pragma unroll
      for (int sub = 0; sub < 4; ++sub) {
        int tt = (t0 + sub * 16 + lq) & 2047;
#pragma unroll
        for (int r = 0; r < 4; ++r) {
          int d = wave * 64 + a * 16 + grp * 4 + r;
          vT[(size_t)b * 128 * 2048 + (size_t)d * 2048 + tt] = (bf16_t)acc[a][sub][r];
        }
      }
  }
}

// ---------------- flash attention v10: kv-split-4, no kf preload (no spill) ---------
// 1024 blocks = 8 b (XCD-pinned) x 128 q-tiles(16 rows), heavy-first; 4 waves/block.
// Per wave: K single-buf LDS (8KB), read directly by QK MFMAs; stageK(i+1) issued
// AFTER QK behind lgkmcnt(0) (reads complete). V single-buf regs, 1 tile ahead.
// vm queue entering iter i: [K(i):8, V(i):8]. Zero loop barriers.
__global__ __launch_bounds__(256, 3) void attn_kernel(const bf16_t* __restrict__ q,
                                                      const bf16_t* __restrict__ k,
                                                      const bf16_t* __restrict__ vT,
                                                      float* __restrict__ out) {
  __shared__ __align__(16) char lds[36864];  // w*8K: K buf (merge: O dump) | 32768+w*1K: P (merge: m/l)

  int tid = threadIdx.x;
  int lane = tid & 63;
  int w = tid >> 6;                  // kv-split index 0..3
  int lq = lane & 15, grp = lane >> 4;
  int b = blockIdx.x & 7;            // XCD-pinned batch
  int qt = 127 - (blockIdx.x >> 3);  // heavy first; 16 q-rows
  int tq = qt * 16 + lq;

  bf16x8 qf[4];
  const bf16_t* qrow = q + ((size_t)b * 2048 + tq) * 128 + grp * 8;
#pragma unroll
  for (int ks = 0; ks < 4; ++ks) qf[ks] = *(const bf16x8*)(qrow + ks * 32);

  float mrun = -__builtin_inff();
  float lsum = 0.f;
  f32x4 accO[8];
#pragma unroll
  for (int i = 0; i < 8; ++i) accO[i] = (f32x4){0.f, 0.f, 0.f, 0.f};

  const char* kbase = (const char*)(k + (size_t)b * 2048 * 128);
  const bf16_t* vb = vT + (size_t)b * 128 * 2048;

  auto stageK = [&](int kv0) {   // 8KB tile [32 kv][256B], per-wave private, XOR swz
#pragma unroll
    for (int i = 0; i < 8; ++i) {
      int off = i * 1024 + lane * 16;
      int row = off >> 8;
      int c = (off >> 4) & 15;
      const char* src = kbase + (size_t)(kv0 + row) * 256 + ((c ^ (row & 7)) << 4);
      g2lds16(src, &lds[w * 8192 + off]);
    }
  };

  bf16x8 vf[8];
  auto loadV = [&](int kv0) {    // V^T frags direct to regs (8 x 16B)
#pragma unroll
    for (int mf = 0; mf < 8; ++mf)
      vf[mf] = *(const bf16x8*)(vb + (size_t)(mf * 16 + lq) * 2048 + kv0 + grp * 8);
  };

  int nt = (qt >> 1) + 1;            // kv tiles of 32 covering [0, qt*16+16)
  int cnt = (nt - w + 3) >> 2;       // tiles w, w+4, ...

  if (cnt > 0) { stageK(w * 32); loadV(w * 32); }

#pragma unroll 1
  for (int i = 0; i < cnt; ++i) {
    int kv0 = (w + 4 * i) * 32;
    bool pre = (i + 1 < cnt);

    WAITVM(8);                       // K(i) landed; V(i) still in flight
    __builtin_amdgcn_sched_barrier(0);

    // S^T = K · Q^T, K fragments read directly from LDS (Q pre-scaled by 1/32)
    f32x4 s[2];
    s[0] = (f32x4){0.f, 0.f, 0.f, 0.f};
    s[1] = (f32x4){0.f, 0.f, 0.f, 0.f};
#pragma unroll
    for (int ks = 0; ks < 4; ++ks)
#pragma unroll
      for (int mf = 0; mf < 2; ++mf) {
        int row = mf * 16 + lq;
        bf16x8 kf = *(const bf16x8*)(&lds[w * 8192 + row * 256
                                          + (((ks * 4 + grp) ^ (row & 7)) << 4)]);
        s[mf] = __builtin_amdgcn_mfma_f32_16x16x32_bf16(kf, qf[ks], s[mf], 0, 0, 0);
      }

    // all K ds_reads consumed (MFMAs issued); safe to overwrite own buffer
    asm volatile("s_waitcnt lgkmcnt(0)" ::: "memory");
    __builtin_amdgcn_sched_barrier(0);
    if (pre) stageK(kv0 + 128);      // queue: [V(i):8, K(i+1):8]

    // online softmax in-place in s; lane owns q-row tq, holds 8 kv values
    bool hasmask = (kv0 + 31 > qt * 16);
    if (hasmask) {
#pragma unroll
      for (int f = 0; f < 2; ++f)
#pragma unroll
        for (int r = 0; r < 4; ++r) {
          int kv = kv0 + f * 16 + grp * 4 + r;
          s[f][r] = (kv <= tq) ? s[f][r] : -__builtin_inff();
        }
    }
    float pmax = -__builtin_inff();
#pragma unroll
    for (int f = 0; f < 2; ++f)
#pragma unroll
      for (int r = 0; r < 4; ++r) pmax = fmaxf(pmax, s[f][r]);
    pmax = fmaxf(pmax, __shfl_xor(pmax, 16, 64));
    pmax = fmaxf(pmax, __shfl_xor(pmax, 32, 64));

    float msub;
    if (__all(pmax <= mrun)) {       // defer-rescale
      msub = mrun;
    } else {
      float mnew = fmaxf(mrun, pmax);
      msub = fmaxf(mnew, -3e38f);    // NaN guard
      float corr = __expf(mrun - msub);
      lsum *= corr;
      mrun = mnew;
#pragma unroll
      for (int i2 = 0; i2 < 8; ++i2) accO[i2] *= corr;
    }

    // fused exp + bf16 pack + psum  (P^T into wave-private 1KB)
    float psum = 0.f;
#pragma unroll
    for (int f = 0; f < 2; ++f) {
      bf16x4 pw;
#pragma unroll
      for (int r = 0; r < 4; ++r) {
        float pe = __expf(s[f][r] - msub);
        psum += pe;
        pw[r] = (bf16_t)pe;
      }
      *(bf16x4*)(&lds[32768 + w * 1024 + ((f * 2 + (grp >> 1)) << 8)
                      + lq * 16 + ((grp & 1) << 3)]) = pw;
    }
    psum += __shfl_xor(psum, 16, 64);
    psum += __shfl_xor(psum, 32, 64);
    lsum += psum;

    if (pre) { WAITVM(8); }          // V(i) regs ready; K(i+1) stays in flight
    else     { WAITVM(0); }
    __builtin_amdgcn_sched_barrier(0);

    // O^T += V^T · P^T
    bf16x8 pf = *(const bf16x8*)(&lds[32768 + w * 1024 + (grp << 8) + lq * 16]);
#pragma unroll
    for (int mf = 0; mf < 8; ++mf)
      accO[mf] = __builtin_amdgcn_mfma_f32_16x16x32_bf16(vf[mf], pf, accO[mf], 0, 0, 0);

    if (pre) loadV(kv0 + 128);       // queue: [K(i+1):8, V(i+1):8]
  }

  // ---- 4-way kv-split merge via LDS (single barrier); K/P regions reused ----
#pragma unroll
  for (int mf = 0; mf < 8; ++mf)
    *(f32x4*)(&lds[w * 8192 + lane * 128 + mf * 16]) = accO[mf];
  *(float*)(&lds[32768 + w * 1024 + lane * 8])     = mrun;
  *(float*)(&lds[32768 + w * 1024 + lane * 8 + 4]) = lsum;
  __syncthreads();

  float mm[4], ll[4];
#pragma unroll
  for (int u = 0; u < 4; ++u) {
    mm[u] = *(const float*)(&lds[32768 + u * 1024 + lane * 8]);
    ll[u] = *(const float*)(&lds[32768 + u * 1024 + lane * 8 + 4]);
  }
  float m = fmaxf(fmaxf(mm[0], mm[1]), fmaxf(mm[2], mm[3]));
  float cc[4], L = 0.f;
#pragma unroll
  for (int u = 0; u < 4; ++u) { cc[u] = __expf(mm[u] - m); L += ll[u] * cc[u]; }
  float inv = 1.0f / L;
  float* orow = out + ((size_t)b * 2048 + tq) * 128;
#pragma unroll
  for (int j = 0; j < 2; ++j) {
    int mf = w * 2 + j;
    f32x4 o = (f32x4){0.f, 0.f, 0.f, 0.f};
#pragma unroll
    for (int u = 0; u < 4; ++u) {
      f32x4 Ou = *(const f32x4*)(&lds[u * 8192 + lane * 128 + mf * 16]);
#pragma unroll
      for (int e = 0; e < 4; ++e) o[e] += Ou[e] * cc[u];
    }
#pragma unroll
    for (int e = 0; e < 4; ++e) o[e] *= inv;
    *(f32x4*)(orow + mf * 16 + grp * 4) = o;
  }
}

extern "C" void kernel_launch(void* const* d_in, const int* in_sizes, int n_in,
                              void* d_out, int out_size, void* d_ws, size_t ws_size,
                              hipStream_t stream) {
  const float* x  = (const float*)d_in[0];
  const float* Wq = (const float*)d_in[1];
  const float* Wk = (const float*)d_in[2];
  const float* Wv = (const float*)d_in[3];
  float* out = (float*)d_out;
  char* ws = (char*)d_ws;

  bf16_t* wt = (bf16_t*)(ws + WT_OFF);
  bf16_t* qb = (bf16_t*)(ws + Q_OFF);
  bf16_t* kb = (bf16_t*)(ws + K_OFF);
  bf16_t* vT = (bf16_t*)(ws + VT_OFF);

  hipLaunchKernelGGL(wt_kernel, dim3(48), dim3(256), 0, stream, Wq, Wk, Wv, wt);
  hipLaunchKernelGGL(proj_kernel, dim3(768), dim3(128), 0, stream, x, wt, qb, kb, vT);
  hipLaunchKernelGGL(attn_kernel, dim3(1024), dim3(256), 0, stream, qb, kb, vT, out);
}

// Round 11
// 78.402 us; speedup vs baseline: 1.5522x; 1.2328x over previous
//
#include <hip/hip_runtime.h>
#include <hip/hip_bf16.h>
#include <stdint.h>

typedef __bf16 bf16_t;
typedef __bf16 bf16x4 __attribute__((ext_vector_type(4)));
typedef __bf16 bf16x8 __attribute__((ext_vector_type(8)));
typedef float  f32x4  __attribute__((ext_vector_type(4)));

#define WAITVM(N) asm volatile("s_waitcnt vmcnt(" #N ")" ::: "memory")

// ---- workspace layout (bytes) ----
static constexpr size_t WT_OFF = 0;                    // Wt bf16 [384][1024] = 768 KB
static constexpr size_t Q_OFF  = (size_t)1 << 20;      // q bf16 (pre-scaled 1/32) 4 MB
static constexpr size_t K_OFF  = Q_OFF + ((size_t)4 << 20);
static constexpr size_t VT_OFF = K_OFF + ((size_t)4 << 20);  // vT bf16 [8][128][2048] = 4 MB

__device__ __forceinline__ void g2lds16(const void* g, void* l) {
  __builtin_amdgcn_global_load_lds(
      (__attribute__((address_space(1))) void*)(g),
      (__attribute__((address_space(3))) void*)(l), 16, 0, 0);
}

// ---------------- W transpose: W[1024][128] fp32 -> Wt[384][1024] bf16 ----------------
__global__ __launch_bounds__(256) void wt_kernel(const float* __restrict__ Wq,
                                                 const float* __restrict__ Wk,
                                                 const float* __restrict__ Wv,
                                                 bf16_t* __restrict__ wt) {
  __shared__ float tile[64][129];
  int wi = blockIdx.x >> 4;
  int ct = blockIdx.x & 15;
  const float* W = (wi == 0) ? Wq : ((wi == 1) ? Wk : Wv);
  int c0 = ct * 64;
  int tid = threadIdx.x;
  for (int i = 0; i < 32; ++i) {
    int idx = i * 256 + tid;
    int c = idx >> 7, n = idx & 127;
    tile[c][n] = W[(size_t)(c0 + c) * 128 + n];
  }
  __syncthreads();
  for (int i = 0; i < 32; ++i) {
    int idx = i * 256 + tid;
    int n = idx >> 6, c = idx & 63;
    wt[(size_t)(wi * 128 + n) * 1024 + c0 + c] = (bf16_t)tile[c][n];
  }
}

// ---------------- fused QKV projection v6 (measured ~33us) + Q prescale -------------
__global__ __launch_bounds__(128) void proj_kernel(const float* __restrict__ x,
                                                   const bf16_t* __restrict__ wt,
                                                   bf16_t* __restrict__ q,
                                                   bf16_t* __restrict__ k,
                                                   bf16_t* __restrict__ vT) {
  __shared__ __align__(16) char Blds[2][16384];  // x tile [64 t][64 k] f32, 16B-chunk XOR swz

  int wgid = (blockIdx.x & 7) * 96 + (blockIdx.x >> 3);
  int t_tile = wgid / 3;
  int slice = wgid % 3;          // 0=Q, 1=K, 2=V
  int n0 = slice * 128;
  int t0 = t_tile * 64;

  int tid = threadIdx.x;
  int lane = tid & 63;
  int wave = tid >> 6;           // n-half
  int lq = lane & 15, grp = lane >> 4;

  const char* xb = (const char*)x;

  f32x4 acc[4][4];
#pragma unroll
  for (int a = 0; a < 4; ++a)
#pragma unroll
    for (int s = 0; s < 4; ++s) acc[a][s] = (f32x4){0.f, 0.f, 0.f, 0.f};

  const bf16_t* wbase = wt + (size_t)(n0 + wave * 64 + lq) * 1024 + grp * 8;

  auto stageB = [&](int bi, int k0) {
#pragma unroll
    for (int i = 0; i < 8; ++i) {
      int off = i * 2048 + tid * 16;
      int row = off >> 8;
      int c = (off >> 4) & 15;
      const char* src = xb + (size_t)(t0 + row) * 4096 + (size_t)k0 * 4
                        + ((c ^ (row & 15)) << 4);
      g2lds16(src, &Blds[bi][off]);
    }
  };

  stageB(0, 0);

  for (int ks = 0; ks < 16; ++ks) {
    int cur = ks & 1;
    int k0 = ks * 64;

    bf16x8 wf[4][2];
#pragma unroll
    for (int kh = 0; kh < 2; ++kh)
#pragma unroll
      for (int a = 0; a < 4; ++a)
        wf[a][kh] = *(const bf16x8*)(wbase + (size_t)(a * 16) * 1024 + k0 + kh * 32);

    if (ks < 15) {
      stageB(cur ^ 1, (ks + 1) * 64);
      WAITVM(16);
    } else {
      WAITVM(8);
    }
    __builtin_amdgcn_s_barrier();
    __builtin_amdgcn_sched_barrier(0);

    bf16x8 xf[4][2];
#pragma unroll
    for (int sub = 0; sub < 4; ++sub) {
      int row = sub * 16 + lq;
#pragma unroll
      for (int kh = 0; kh < 2; ++kh) {
        int c0 = kh * 8 + grp * 2;
        float4 f0 = *(const float4*)(&Blds[cur][row * 256 + (((c0)     ^ (row & 15)) << 4)]);
        float4 f1 = *(const float4*)(&Blds[cur][row * 256 + (((c0 + 1) ^ (row & 15)) << 4)]);
        bf16x8 v;
        v[0] = (bf16_t)f0.x; v[1] = (bf16_t)f0.y; v[2] = (bf16_t)f0.z; v[3] = (bf16_t)f0.w;
        v[4] = (bf16_t)f1.x; v[5] = (bf16_t)f1.y; v[6] = (bf16_t)f1.z; v[7] = (bf16_t)f1.w;
        xf[sub][kh] = v;
      }
    }

#pragma unroll
    for (int kh = 0; kh < 2; ++kh)
#pragma unroll
      for (int a = 0; a < 4; ++a)
#pragma unroll
        for (int sub = 0; sub < 4; ++sub)
          acc[a][sub] = __builtin_amdgcn_mfma_f32_16x16x32_bf16(wf[a][kh], xf[sub][kh],
                                                                acc[a][sub], 0, 0, 0);
    __builtin_amdgcn_s_barrier();
  }

  if (slice < 2) {
    bf16_t* dst = (slice == 0) ? q : k;
    float qs = (slice == 0) ? 0.03125f : 1.0f;
#pragma unroll
    for (int a = 0; a < 4; ++a)
#pragma unroll
      for (int sub = 0; sub < 4; ++sub) {
        bf16x4 o;
        o[0] = (bf16_t)(acc[a][sub][0] * qs); o[1] = (bf16_t)(acc[a][sub][1] * qs);
        o[2] = (bf16_t)(acc[a][sub][2] * qs); o[3] = (bf16_t)(acc[a][sub][3] * qs);
        *(bf16x4*)(dst + (size_t)(t0 + sub * 16 + lq) * 128 + wave * 64 + a * 16 + grp * 4) = o;
      }
  } else {
    int b = t0 >> 11;
#pragma unroll
    for (int a = 0; a < 4; ++a)
#pragma unroll
      for (int sub = 0; sub < 4; ++sub) {
        int tt = (t0 + sub * 16 + lq) & 2047;
#pragma unroll
        for (int r = 0; r < 4; ++r) {
          int d = wave * 64 + a * 16 + grp * 4 + r;
          vT[(size_t)b * 128 * 2048 + (size_t)d * 2048 + tt] = (bf16_t)acc[a][sub][r];
        }
      }
  }
}

// ---------------- flash attention v11: 32 q-rows/wave, kv-split-8 -------------------
// 512 blocks = 8 b (XCD-pinned) x 64 q-tiles(32 rows), heavy-first; 8 waves/block.
// Each wave: TWO 16-row q-groups (qh) sharing one K-LDS tile + V-regs -> 2x MFMA/byte,
// KV traffic halved. Per-wave pipeline from R10 (no loop barriers, counted vmcnt).
// LDS 80KB: w*8K K bufs (64K) | 65536 + w*2K P bufs. Merge: 3-round LDS tree.
__global__ __launch_bounds__(512) void attn_kernel(const bf16_t* __restrict__ q,
                                                   const bf16_t* __restrict__ k,
                                                   const bf16_t* __restrict__ vT,
                                                   float* __restrict__ out) {
  __shared__ __align__(16) char lds[81920];

  int tid = threadIdx.x;
  int lane = tid & 63;
  int w = tid >> 6;                  // kv-split index 0..7
  int lq = lane & 15, grp = lane >> 4;
  int b = blockIdx.x & 7;            // XCD-pinned batch
  int qt = 63 - (blockIdx.x >> 3);   // heavy first; 32 q-rows
  int tq0 = qt * 32 + lq;            // qh=0 row; qh=1 row = tq0+16

  bf16x8 qf[4][2];
#pragma unroll
  for (int qh = 0; qh < 2; ++qh) {
    const bf16_t* qrow = q + ((size_t)b * 2048 + tq0 + qh * 16) * 128 + grp * 8;
#pragma unroll
    for (int ks = 0; ks < 4; ++ks) qf[ks][qh] = *(const bf16x8*)(qrow + ks * 32);
  }

  float mrun[2] = {-__builtin_inff(), -__builtin_inff()};
  float lsum[2] = {0.f, 0.f};
  f32x4 accO[8][2];
#pragma unroll
  for (int i = 0; i < 8; ++i)
#pragma unroll
    for (int qh = 0; qh < 2; ++qh) accO[i][qh] = (f32x4){0.f, 0.f, 0.f, 0.f};

  const char* kbase = (const char*)(k + (size_t)b * 2048 * 128);
  const bf16_t* vb = vT + (size_t)b * 128 * 2048;

  auto stageK = [&](int kv0) {   // 8KB tile [32 kv][256B], per-wave private, XOR swz
#pragma unroll
    for (int i = 0; i < 8; ++i) {
      int off = i * 1024 + lane * 16;
      int row = off >> 8;
      int c = (off >> 4) & 15;
      const char* src = kbase + (size_t)(kv0 + row) * 256 + ((c ^ (row & 7)) << 4);
      g2lds16(src, &lds[w * 8192 + off]);
    }
  };

  bf16x8 vf[8];
  auto loadV = [&](int kv0) {
#pragma unroll
    for (int mf = 0; mf < 8; ++mf)
      vf[mf] = *(const bf16x8*)(vb + (size_t)(mf * 16 + lq) * 2048 + kv0 + grp * 8);
  };

  int nt = qt + 1;                   // kv tiles of 32 covering [0, qt*32+32)
  int cnt = (nt - w + 7) >> 3;       // tiles w, w+8, ...

  if (cnt > 0) { stageK(w * 32); loadV(w * 32); }

#pragma unroll 1
  for (int i = 0; i < cnt; ++i) {
    int kv0 = (w + 8 * i) * 32;
    bool pre = (i + 1 < cnt);

    WAITVM(8);                       // K(i) landed; V(i) in flight
    __builtin_amdgcn_sched_barrier(0);

    // S^T = K · Q^T for both q-groups; K frags read once, used twice
    f32x4 s[2][2];
#pragma unroll
    for (int mf = 0; mf < 2; ++mf)
#pragma unroll
      for (int qh = 0; qh < 2; ++qh) s[mf][qh] = (f32x4){0.f, 0.f, 0.f, 0.f};
#pragma unroll
    for (int ks = 0; ks < 4; ++ks)
#pragma unroll
      for (int mf = 0; mf < 2; ++mf) {
        int row = mf * 16 + lq;
        bf16x8 kf = *(const bf16x8*)(&lds[w * 8192 + row * 256
                                          + (((ks * 4 + grp) ^ (row & 7)) << 4)]);
#pragma unroll
        for (int qh = 0; qh < 2; ++qh)
          s[mf][qh] = __builtin_amdgcn_mfma_f32_16x16x32_bf16(kf, qf[ks][qh], s[mf][qh], 0, 0, 0);
      }

    asm volatile("s_waitcnt lgkmcnt(0)" ::: "memory");
    __builtin_amdgcn_sched_barrier(0);
    if (pre) stageK(kv0 + 256);      // queue: [V(i):8, K(i+1):8]

    // online softmax per q-group
#pragma unroll
    for (int qh = 0; qh < 2; ++qh) {
      int tq = tq0 + qh * 16;
      bool hasmask = (kv0 + 31 > qt * 32 + qh * 16);
      if (hasmask) {
#pragma unroll
        for (int f = 0; f < 2; ++f)
#pragma unroll
          for (int r = 0; r < 4; ++r) {
            int kv = kv0 + f * 16 + grp * 4 + r;
            s[f][qh][r] = (kv <= tq) ? s[f][qh][r] : -__builtin_inff();
          }
      }
      float pmax = -__builtin_inff();
#pragma unroll
      for (int f = 0; f < 2; ++f)
#pragma unroll
        for (int r = 0; r < 4; ++r) pmax = fmaxf(pmax, s[f][qh][r]);
      pmax = fmaxf(pmax, __shfl_xor(pmax, 16, 64));
      pmax = fmaxf(pmax, __shfl_xor(pmax, 32, 64));

      float msub;
      if (__all(pmax <= mrun[qh])) {
        msub = mrun[qh];
      } else {
        float mnew = fmaxf(mrun[qh], pmax);
        msub = fmaxf(mnew, -3e38f);
        float corr = __expf(mrun[qh] - msub);
        lsum[qh] *= corr;
        mrun[qh] = mnew;
#pragma unroll
        for (int i2 = 0; i2 < 8; ++i2) accO[i2][qh] *= corr;
      }

      float psum = 0.f;
#pragma unroll
      for (int f = 0; f < 2; ++f) {
        bf16x4 pw;
#pragma unroll
        for (int r = 0; r < 4; ++r) {
          float pe = __expf(s[f][qh][r] - msub);
          psum += pe;
          pw[r] = (bf16_t)pe;
        }
        *(bf16x4*)(&lds[65536 + w * 2048 + qh * 1024 + ((f * 2 + (grp >> 1)) << 8)
                        + lq * 16 + ((grp & 1) << 3)]) = pw;
      }
      psum += __shfl_xor(psum, 16, 64);
      psum += __shfl_xor(psum, 32, 64);
      lsum[qh] += psum;
    }

    if (pre) { WAITVM(8); }          // V(i) ready; K(i+1) in flight
    else     { WAITVM(0); }
    __builtin_amdgcn_sched_barrier(0);

    // O^T += V^T · P^T for both q-groups (V regs shared)
    bf16x8 pf0 = *(const bf16x8*)(&lds[65536 + w * 2048 + (grp << 8) + lq * 16]);
    bf16x8 pf1 = *(const bf16x8*)(&lds[65536 + w * 2048 + 1024 + (grp << 8) + lq * 16]);
#pragma unroll
    for (int mf = 0; mf < 8; ++mf) {
      accO[mf][0] = __builtin_amdgcn_mfma_f32_16x16x32_bf16(vf[mf], pf0, accO[mf][0], 0, 0, 0);
      accO[mf][1] = __builtin_amdgcn_mfma_f32_16x16x32_bf16(vf[mf], pf1, accO[mf][1], 0, 0, 0);
    }

    if (pre) loadV(kv0 + 256);       // queue: [K(i+1):8, V(i+1):8]
  }

  // ---- 8-way kv-split merge: 3-round LDS tree (dump region reuses K bufs, 64KB) ----
  // partial dump layout: slot*16384 + qh*8192 + mf*1024 + lane*16 (f32x4)
  // m/l dump: 65536 + w*2048 + qh*512 + lane*8 (m at +0, l at +4)
#pragma unroll 1
  for (int round = 0; round < 3; ++round) {
    int stride = 4 >> round;               // 4, 2, 1
    __syncthreads();
    if (w >= stride && w < 2 * stride) {   // dump waves
      int slot = w - stride;
#pragma unroll
      for (int qh = 0; qh < 2; ++qh) {
#pragma unroll
        for (int mf = 0; mf < 8; ++mf)
          *(f32x4*)(&lds[slot * 16384 + qh * 8192 + mf * 1024 + lane * 16]) = accO[mf][qh];
        *(float*)(&lds[65536 + w * 2048 + qh * 512 + lane * 8])     = mrun[qh];
        *(float*)(&lds[65536 + w * 2048 + qh * 512 + lane * 8 + 4]) = lsum[qh];
      }
    }
    __syncthreads();
    if (w < stride) {                      // combine waves
      int pw = w + stride;
#pragma unroll
      for (int qh = 0; qh < 2; ++qh) {
        float mB = *(const float*)(&lds[65536 + pw * 2048 + qh * 512 + lane * 8]);
        float lB = *(const float*)(&lds[65536 + pw * 2048 + qh * 512 + lane * 8 + 4]);
        float mN = fmaxf(mrun[qh], mB);
        float ms = fmaxf(mN, -3e38f);
        float cA = __expf(mrun[qh] - ms);
        float cB = __expf(mB - ms);
        lsum[qh] = lsum[qh] * cA + lB * cB;
        mrun[qh] = mN;
#pragma unroll
        for (int mf = 0; mf < 8; ++mf) {
          f32x4 OB = *(const f32x4*)(&lds[w * 16384 + qh * 8192 + mf * 1024 + lane * 16]);
#pragma unroll
          for (int e = 0; e < 4; ++e) accO[mf][qh][e] = accO[mf][qh][e] * cA + OB[e] * cB;
        }
      }
    }
  }

  if (w == 0) {
#pragma unroll
    for (int qh = 0; qh < 2; ++qh) {
      float inv = 1.0f / lsum[qh];
      float* orow = out + ((size_t)b * 2048 + tq0 + qh * 16) * 128;
#pragma unroll
      for (int mf = 0; mf < 8; ++mf) {
        f32x4 o;
#pragma unroll
        for (int e = 0; e < 4; ++e) o[e] = accO[mf][qh][e] * inv;
        *(f32x4*)(orow + mf * 16 + grp * 4) = o;
      }
    }
  }
}

extern "C" void kernel_launch(void* const* d_in, const int* in_sizes, int n_in,
                              void* d_out, int out_size, void* d_ws, size_t ws_size,
                              hipStream_t stream) {
  const float* x  = (const float*)d_in[0];
  const float* Wq = (const float*)d_in[1];
  const float* Wk = (const float*)d_in[2];
  const float* Wv = (const float*)d_in[3];
  float* out = (float*)d_out;
  char* ws = (char*)d_ws;

  bf16_t* wt = (bf16_t*)(ws + WT_OFF);
  bf16_t* qb = (bf16_t*)(ws + Q_OFF);
  bf16_t* kb = (bf16_t*)(ws + K_OFF);
  bf16_t* vT = (bf16_t*)(ws + VT_OFF);

  hipLaunchKernelGGL(wt_kernel, dim3(48), dim3(256), 0, stream, Wq, Wk, Wv, wt);
  hipLaunchKernelGGL(proj_kernel, dim3(768), dim3(128), 0, stream, x, wt, qb, kb, vT);
  hipLaunchKernelGGL(attn_kernel, dim3(512), dim3(512), 0, stream, qb, kb, vT, out);
}